// Round 7
// baseline (300.390 us; speedup 1.0000x reference)
//
#include <hip/hip_runtime.h>
#include <hip/hip_bf16.h>

#define Bb   4
#define Hh   16
#define Ss   2048
#define Dd   128
#define QBLK 128
#define KVB  64

typedef __attribute__((ext_vector_type(8))) short bf16x8;
typedef __attribute__((ext_vector_type(4))) float f32x4;
typedef __attribute__((ext_vector_type(4))) float fvec4;
typedef __attribute__((ext_vector_type(2))) unsigned u32x2;
typedef __attribute__((ext_vector_type(4))) unsigned u32x4;

__device__ __forceinline__ unsigned pk2(float a, float b) {
    __hip_bfloat162 h = __float22bfloat162_rn(make_float2(a, b));
    unsigned u; __builtin_memcpy(&u, &h, 4); return u;
}

typedef const __attribute__((address_space(1))) char* gas_t;
typedef __attribute__((address_space(3))) char* las_t;
__device__ __forceinline__ void gld16(const void* g, void* l) {
    __builtin_amdgcn_global_load_lds((gas_t)g, (las_t)l, 16, 0, 0);
}

// ---------- prepass A: K fp32 [bh][s][d] -> bf16 same layout ----------
__global__ __launch_bounds__(256) void cvtk_kernel(const float* __restrict__ K,
                                                   short* __restrict__ Kb) {
    size_t i = ((size_t)blockIdx.x * 256 + threadIdx.x) * 8;
    fvec4 a = ((const fvec4*)(K + i))[0];
    fvec4 b = ((const fvec4*)(K + i))[1];
    u32x4 u;
    u[0] = pk2(a[0], a[1]); u[1] = pk2(a[2], a[3]);
    u[2] = pk2(b[0], b[1]); u[3] = pk2(b[2], b[3]);
    *(u32x4*)(Kb + i) = u;
}

// ---------- prepass B: V fp32 [bh][s][d] -> fragment tiles + partial col sums ----------
// Vf[bh][kt][dt][cc][lane][8bf16]; lane=(g<<4)|qc holds V[s=kt*64+cc*32+g*8+j][d=dt*16+qc]
__global__ __launch_bounds__(256) void cvtvf_kernel(const float* __restrict__ V,
                                                    short* __restrict__ Vf,
                                                    float* __restrict__ part) {
    __shared__ float bins[128];
    const int bh = blockIdx.x >> 5, kt = blockIdx.x & 31;
    const int tid = threadIdx.x;
    if (tid < 128) bins[tid] = 0.f;
    __syncthreads();
    const float* Vb = V + ((size_t)bh * Ss + kt * 64) * Dd;
    short* out = Vf + ((size_t)(bh * 32 + kt)) * 8192;
    #pragma unroll
    for (int i = 0; i < 4; ++i) {
        int c = tid + 256 * i;
        int dt = c >> 7, cc = (c >> 6) & 1, l = c & 63;
        int g = l >> 4, qc = l & 15;
        int d = dt * 16 + qc;
        const float* src = Vb + (size_t)(cc * 32 + g * 8) * Dd + d;
        float v[8]; float s = 0.f;
        #pragma unroll
        for (int j = 0; j < 8; ++j) { v[j] = src[(size_t)j * Dd]; s += v[j]; }
        atomicAdd(&bins[d], s);
        u32x4 u;
        u[0] = pk2(v[0], v[1]); u[1] = pk2(v[2], v[3]);
        u[2] = pk2(v[4], v[5]); u[3] = pk2(v[6], v[7]);
        *(u32x4*)(out + c * 8) = u;
    }
    __syncthreads();
    if (tid < 128) part[(size_t)blockIdx.x * Dd + tid] = bins[tid];
}

// ---------- fallback partial V sums ----------
__global__ __launch_bounds__(256) void vpart_kernel(const float* __restrict__ V,
                                                    float* __restrict__ part) {
    int blk = blockIdx.x, bh = blk >> 3, ch = blk & 7;
    int tid = threadIdx.x, d4 = tid & 31, rg = tid >> 5;
    const fvec4* p = (const fvec4*)(V + ((size_t)bh * Ss + ch * 256) * Dd) + d4;
    fvec4 s = {0.f, 0.f, 0.f, 0.f};
    for (int rr = 0; rr < 32; ++rr) s += p[(size_t)(rg * 32 + rr) * 32];
    __shared__ fvec4 red[256];
    red[tid] = s;
    __syncthreads();
    for (int off = 128; off >= 32; off >>= 1) {
        if (tid < off) red[tid] += red[tid + off];
        __syncthreads();
    }
    if (tid < 32) ((fvec4*)(part + (size_t)blk * Dd))[tid] = red[tid];
}

// ---------- combine partials -> vmean ----------
__global__ __launch_bounds__(128) void vcomb_kernel(const float* __restrict__ part,
                                                    float* __restrict__ vm, int nch) {
    int bh = blockIdx.x, d = threadIdx.x;
    float s = 0.f;
    for (int c = 0; c < nch; ++c) s += part[(size_t)(bh * nch + c) * Dd + d];
    vm[bh * Dd + d] = s * (1.0f / 2048.0f);
}

// ====== flash attention: K via DMA-dbuf LDS, V direct-from-L2 fragments ======
// LDS 48KB -> 3 blocks/CU. 1 barrier per KV tile.
__global__ __launch_bounds__(256, 3) void attn3_kernel(
    const float* __restrict__ Qg, const short* __restrict__ Kbf,
    const short* __restrict__ Vf, const int* __restrict__ slen,
    const float* __restrict__ vmean, float* __restrict__ Og)
{
    __shared__ __align__(16) short Ks[2][KVB * Dd];    // 2 x 16KB
    __shared__ __align__(16) short Ps[4 * 2048];       // 16KB (4KB/wave)

    const int bid = blockIdx.x;
    const int qslot = bid >> 6, r = bid & 63;
    const int qt = 15 - qslot;                         // deepest q-tiles first
    const int b  = (r >> 3) & 3;                       // every batch on every XCD
    const int h  = (r & 7) | ((r >> 5) << 3);
    const int bh = b * 16 + h;                         // (b,h)'s q-tiles share XCD
    const int len = slen[b];
    const int q0 = qt * QBLK;
    const int tid = threadIdx.x;

    if (q0 >= len) {                                   // fully-invalid: rows = mean(V)
        const fvec4* vm4 = (const fvec4*)(vmean + bh * Dd);
        fvec4 val = vm4[tid & 31];
        float* ob = Og + ((size_t)bh * Ss + q0) * Dd;
        int r0 = tid >> 5;
        #pragma unroll
        for (int i = 0; i < 16; ++i)
            ((fvec4*)(ob + (size_t)(r0 + 8 * i) * Dd))[tid & 31] = val;
        return;
    }

    const int w = tid >> 6, lane = tid & 63;
    const int g = lane >> 4, qc = lane & 15;
    const int qw0 = q0 + w * 32;
    const bool wave_active = (qw0 < len);
    const int lo16 = lane * 16;

    const int kv_end   = min(q0 + QBLK, len);
    const int kv_end_w = min(qw0 + 32, kv_end);
    const int nt = (kv_end + KVB - 1) >> 6;

    // K DMA constants: 16B-granule XOR swizzle baked into global source (R4-proven)
    int CK[4];
    const char* KbhB = (const char*)Kbf + (size_t)bh * Ss * 256;
    const char* VfB  = (const char*)Vf + (size_t)bh * 524288;
    #pragma unroll
    for (int i = 0; i < 4; ++i) {
        int krow = w * 16 + i * 4 + (lane >> 4);
        int jK = lane & 15;
        int jKs = (jK & 8) | ((jK & 7) ^ (krow & 7));
        CK[i] = krow * 256 + jKs * 16;
    }

    #define KISSUE(tile_, buf_) do {                                                   \
        size_t kb_ = (size_t)(tile_) * (KVB * 256);                                    \
        _Pragma("unroll")                                                              \
        for (int i_ = 0; i_ < 4; ++i_)                                                 \
            gld16(KbhB + kb_ + CK[i_], (char*)Ks[buf_] + w * 4096 + i_ * 1024);        \
    } while (0)

    KISSUE(0, 0);                                      // tile-0 DMA under Q load

    const float SC = 0.12752870368768582f;             // log2(e)/sqrt(128)
    bf16x8 qf[2][4];
    #pragma unroll
    for (int t2 = 0; t2 < 2; ++t2) {
        const float* qrow = Qg + ((size_t)bh * Ss + (qw0 + 16 * t2 + qc)) * Dd;
        #pragma unroll
        for (int kc = 0; kc < 4; ++kc) {
            const fvec4* p = (const fvec4*)(qrow + kc * 32 + g * 8);
            fvec4 a = p[0], bv = p[1];
            unsigned* fu = (unsigned*)&qf[t2][kc];
            fu[0] = pk2(a[0] * SC, a[1] * SC);
            fu[1] = pk2(a[2] * SC, a[3] * SC);
            fu[2] = pk2(bv[0] * SC, bv[1] * SC);
            fu[3] = pk2(bv[2] * SC, bv[3] * SC);
        }
    }

    asm volatile("s_waitcnt vmcnt(0)" ::: "memory");
    __syncthreads();

    f32x4 o[2][8];
    #pragma unroll
    for (int t2 = 0; t2 < 2; ++t2)
        #pragma unroll
        for (int dt = 0; dt < 8; ++dt) o[t2][dt] = (f32x4){0.f, 0.f, 0.f, 0.f};
    float m_[2]   = {-3e38f, -3e38f};
    float lsum[2] = {0.f, 0.f};

    char* PsB = (char*)Ps + w * 4096;

    for (int t = 0; t < nt; ++t) {
        const int kv0 = t * KVB;
        const int cur = t & 1;
        const bool pre = (t + 1 < nt);
        const bool active = wave_active && (kv0 < kv_end_w);

        if (pre) KISSUE(t + 1, cur ^ 1);               // next K DMA under compute

        if (active) {
            const char* KsB = (const char*)Ks[cur];
            const char* Vtile = VfB + (size_t)t * 16384;

            // ---- QK^T from LDS ----
            f32x4 sa[2][4];
            #pragma unroll
            for (int t2 = 0; t2 < 2; ++t2)
                #pragma unroll
                for (int mt = 0; mt < 4; ++mt) sa[t2][mt] = (f32x4){0.f, 0.f, 0.f, 0.f};
            __builtin_amdgcn_s_setprio(1);
            #pragma unroll
            for (int mt = 0; mt < 4; ++mt) {
                int row = mt * 16 + qc;
                bf16x8 kf[4];
                #pragma unroll
                for (int kc = 0; kc < 4; ++kc) {
                    int jb = kc * 4 + g;
                    int js = (jb & 8) | ((jb & 7) ^ (row & 7));
                    kf[kc] = *(const bf16x8*)(KsB + row * 256 + js * 16);
                }
                #pragma unroll
                for (int t2 = 0; t2 < 2; ++t2)
                    #pragma unroll
                    for (int kc = 0; kc < 4; ++kc)
                        sa[t2][mt] = __builtin_amdgcn_mfma_f32_16x16x32_bf16(
                            kf[kc], qf[t2][kc], sa[t2][mt], 0, 0, 0);
            }
            __builtin_amdgcn_s_setprio(0);

            // ---- prefetch V cc=0 fragments: L2 latency hides under softmax ----
            bf16x8 v0[8];
            #pragma unroll
            for (int dt = 0; dt < 8; ++dt)
                v0[dt] = *(const bf16x8*)(Vtile + (dt * 2) * 1024 + lo16);

            // ---- mask + online softmax (defer-max) ----
            #pragma unroll
            for (int t2 = 0; t2 < 2; ++t2) {
                const int qrow = qw0 + 16 * t2 + qc;
                const bool full = (kv0 + KVB - 1) <= (qw0 + 16 * t2);
                if (!full) {
                    #pragma unroll
                    for (int mt = 0; mt < 4; ++mt)
                        #pragma unroll
                        for (int rr = 0; rr < 4; ++rr) {
                            int kk = kv0 + mt * 16 + g * 4 + rr;
                            if (kk > qrow) sa[t2][mt][rr] = -3e38f;
                        }
                }
                float tm = sa[t2][0][0];
                #pragma unroll
                for (int mt = 0; mt < 4; ++mt)
                    #pragma unroll
                    for (int rr = 0; rr < 4; ++rr) tm = fmaxf(tm, sa[t2][mt][rr]);
                tm = fmaxf(tm, __shfl_xor(tm, 16));
                tm = fmaxf(tm, __shfl_xor(tm, 32));
                if (__any(tm > m_[t2] + 8.0f)) {
                    float mnew = fmaxf(m_[t2], tm);
                    float al = exp2f(m_[t2] - mnew);
                    m_[t2] = mnew;
                    lsum[t2] *= al;
                    #pragma unroll
                    for (int rr = 0; rr < 4; ++rr) {
                        float alr = __shfl(al, g * 4 + rr);
                        #pragma unroll
                        for (int dt = 0; dt < 8; ++dt) o[t2][dt][rr] *= alr;
                    }
                }
                float mref = m_[t2];
                float ls = 0.f;
                int prow = t2 * 16 + qc;
                int pswz = (prow & 7) << 4;
                #pragma unroll
                for (int mt = 0; mt < 4; ++mt) {
                    f32x4 p;
                    #pragma unroll
                    for (int rr = 0; rr < 4; ++rr)
                        p[rr] = exp2f(sa[t2][mt][rr] - mref);
                    ls += (p[0] + p[1]) + (p[2] + p[3]);
                    u32x2 pw;
                    pw[0] = pk2(p[0], p[1]);
                    pw[1] = pk2(p[2], p[3]);
                    *(u32x2*)(PsB + ((prow * 128 + mt * 32 + g * 8) ^ pswz)) = pw;
                }
                lsum[t2] += ls;
            }

            // ---- PV: cc=0 from prefetched regs; cc=1 loaded in-loop ----
            bf16x8 ap[2][2];
            #pragma unroll
            for (int t2 = 0; t2 < 2; ++t2) {
                int prow = t2 * 16 + qc;
                int pswz = (prow & 7) << 4;
                #pragma unroll
                for (int c = 0; c < 2; ++c)
                    ap[t2][c] = *(const bf16x8*)(PsB + ((prow * 128 + c * 64 + g * 16) ^ pswz));
            }
            bf16x8 v1[8];
            #pragma unroll
            for (int dt = 0; dt < 8; ++dt)
                v1[dt] = *(const bf16x8*)(Vtile + (dt * 2 + 1) * 1024 + lo16);
            __builtin_amdgcn_s_setprio(1);
            #pragma unroll
            for (int dt = 0; dt < 8; ++dt)
                #pragma unroll
                for (int t2 = 0; t2 < 2; ++t2)
                    o[t2][dt] = __builtin_amdgcn_mfma_f32_16x16x32_bf16(
                        ap[t2][0], v0[dt], o[t2][dt], 0, 0, 0);
            #pragma unroll
            for (int dt = 0; dt < 8; ++dt)
                #pragma unroll
                for (int t2 = 0; t2 < 2; ++t2)
                    o[t2][dt] = __builtin_amdgcn_mfma_f32_16x16x32_bf16(
                        ap[t2][1], v1[dt], o[t2][dt], 0, 0, 0);
            __builtin_amdgcn_s_setprio(0);
        }

        asm volatile("s_waitcnt vmcnt(0)" ::: "memory");
        __syncthreads();
    }
    #undef KISSUE

    // ---- epilogue ----
    float inv_[2][4];
    #pragma unroll
    for (int t2 = 0; t2 < 2; ++t2) {
        float L = lsum[t2];
        L += __shfl_xor(L, 16);
        L += __shfl_xor(L, 32);
        #pragma unroll
        for (int rr = 0; rr < 4; ++rr) {
            float Lr = __shfl(L, g * 4 + rr);
            inv_[t2][rr] = 1.0f / Lr;
        }
    }
    bool needvm = (qw0 + 32 > len);
    float vmv[8];
    #pragma unroll
    for (int dt = 0; dt < 8; ++dt)
        vmv[dt] = needvm ? vmean[bh * Dd + dt * 16 + qc] : 0.f;
    #pragma unroll
    for (int t2 = 0; t2 < 2; ++t2)
        #pragma unroll
        for (int rr = 0; rr < 4; ++rr) {
            int rowg = qw0 + t2 * 16 + g * 4 + rr;
            float* orow = Og + ((size_t)bh * Ss + rowg) * Dd + qc;
            #pragma unroll
            for (int dt = 0; dt < 8; ++dt) {
                float val = o[t2][dt][rr] * inv_[t2][rr];
                if (rowg >= len) val = vmv[dt];
                orow[dt * 16] = val;
            }
        }
}

// ================= fallback (ws too small): 4-wave in-kernel cvt =================
__global__ __launch_bounds__(256, 2) void attn_fb_kernel(
    const float* __restrict__ Qg, const float* __restrict__ Kg,
    const float* __restrict__ Vg, const int* __restrict__ slen,
    const float* __restrict__ vmean, float* __restrict__ Og)
{
    __shared__ __align__(16) short Ks[KVB * Dd];
    __shared__ __align__(16) short Vt[Dd * KVB];
    __shared__ __align__(16) short Ps[4 * 32 * KVB];

    const int bid = blockIdx.x;
    const int qslot = bid >> 6, r = bid & 63;
    const int qt = 15 - qslot;
    const int b  = (r >> 3) & 3;
    const int h  = (r & 7) | ((r >> 5) << 3);
    const int bh = b * 16 + h;
    const int len = slen[b];
    const int q0 = qt * QBLK;
    const int tid = threadIdx.x;

    if (q0 >= len) {
        const fvec4* vm4 = (const fvec4*)(vmean + bh * Dd);
        fvec4 val = vm4[tid & 31];
        float* ob = Og + ((size_t)bh * Ss + q0) * Dd;
        int r0 = tid >> 5;
        #pragma unroll
        for (int i = 0; i < 16; ++i)
            ((fvec4*)(ob + (size_t)(r0 + 8 * i) * Dd))[tid & 31] = val;
        return;
    }

    const int w = tid >> 6, lane = tid & 63;
    const int g = lane >> 4, qc = lane & 15;
    const int qw0 = q0 + w * 32;
    const bool wave_active = (qw0 < len);

    const int kv_end   = min(q0 + QBLK, len);
    const int kv_end_w = min(qw0 + 32, kv_end);
    const int nt = (kv_end + KVB - 1) >> 6;

    const float SC = 0.12752870368768582f;
    bf16x8 qf[2][4];
    #pragma unroll
    for (int t2 = 0; t2 < 2; ++t2) {
        const float* qrow = Qg + ((size_t)bh * Ss + (qw0 + 16 * t2 + qc)) * Dd;
        #pragma unroll
        for (int kc = 0; kc < 4; ++kc) {
            const fvec4* p = (const fvec4*)(qrow + kc * 32 + g * 8);
            fvec4 a = p[0], bv = p[1];
            unsigned* fu = (unsigned*)&qf[t2][kc];
            fu[0] = pk2(a[0] * SC, a[1] * SC);
            fu[1] = pk2(a[2] * SC, a[3] * SC);
            fu[2] = pk2(bv[0] * SC, bv[1] * SC);
            fu[3] = pk2(bv[2] * SC, bv[3] * SC);
        }
    }

    f32x4 o[2][8];
    #pragma unroll
    for (int t2 = 0; t2 < 2; ++t2)
        #pragma unroll
        for (int dt = 0; dt < 8; ++dt) o[t2][dt] = (f32x4){0.f, 0.f, 0.f, 0.f};
    float m_[2]   = {-3e38f, -3e38f};
    float lsum[2] = {0.f, 0.f};
    char* PsB = (char*)Ps + w * 4096;

    for (int t = 0; t < nt; ++t) {
        const int kv0 = t * KVB;
        const bool active = wave_active && (kv0 < kv_end_w);
        __syncthreads();
        {
            const fvec4* sk = (const fvec4*)(Kg + ((size_t)bh * Ss + kv0) * Dd);
            #pragma unroll
            for (int i = 0; i < 8; ++i) {
                int f = tid + 256 * i;
                int kr = f >> 5, d4 = f & 31;
                fvec4 v = sk[(size_t)kr * 32 + d4];
                u32x2 pr; pr[0] = pk2(v[0], v[1]); pr[1] = pk2(v[2], v[3]);
                int j = d4 >> 1;
                int js = (j & 8) | ((j & 7) ^ (kr & 7));
                *(u32x2*)((char*)Ks + kr * 256 + js * 16 + (d4 & 1) * 8) = pr;
            }
            const float* sv = Vg + ((size_t)bh * Ss + kv0) * Dd;
            #pragma unroll
            for (int i = 0; i < 2; ++i) {
                int idx = tid + 256 * i;
                int dt4 = idx & 31, kt4 = idx >> 5;
                fvec4 vv[4];
                #pragma unroll
                for (int jj = 0; jj < 4; ++jj)
                    vv[jj] = ((const fvec4*)(sv + (size_t)(kt4 * 4 + jj) * Dd))[dt4];
                #pragma unroll
                for (int jj = 0; jj < 4; ++jj) {
                    int d = dt4 * 4 + jj;
                    u32x2 pr;
                    pr[0] = pk2(vv[0][jj], vv[1][jj]);
                    pr[1] = pk2(vv[2][jj], vv[3][jj]);
                    int bo = d * 128 + ((kt4 >> 1) ^ (d & 7)) * 16 + (kt4 & 1) * 8;
                    *(u32x2*)((char*)Vt + bo) = pr;
                }
            }
        }
        __syncthreads();

        if (active) {
            f32x4 sa[2][4];
            #pragma unroll
            for (int t2 = 0; t2 < 2; ++t2)
                #pragma unroll
                for (int mt = 0; mt < 4; ++mt) sa[t2][mt] = (f32x4){0.f, 0.f, 0.f, 0.f};
            #pragma unroll
            for (int mt = 0; mt < 4; ++mt) {
                int row = mt * 16 + qc;
                bf16x8 kf[4];
                #pragma unroll
                for (int kc = 0; kc < 4; ++kc) {
                    int jb = kc * 4 + g;
                    int js = (jb & 8) | ((jb & 7) ^ (row & 7));
                    kf[kc] = *(const bf16x8*)((const char*)Ks + row * 256 + js * 16);
                }
                #pragma unroll
                for (int t2 = 0; t2 < 2; ++t2)
                    #pragma unroll
                    for (int kc = 0; kc < 4; ++kc)
                        sa[t2][mt] = __builtin_amdgcn_mfma_f32_16x16x32_bf16(
                            kf[kc], qf[t2][kc], sa[t2][mt], 0, 0, 0);
            }
            #pragma unroll
            for (int t2 = 0; t2 < 2; ++t2) {
                const int qrow = qw0 + 16 * t2 + qc;
                const bool full = (kv0 + KVB - 1) <= (qw0 + 16 * t2);
                if (!full) {
                    #pragma unroll
                    for (int mt = 0; mt < 4; ++mt)
                        #pragma unroll
                        for (int rr = 0; rr < 4; ++rr) {
                            int kk = kv0 + mt * 16 + g * 4 + rr;
                            if (kk > qrow) sa[t2][mt][rr] = -3e38f;
                        }
                }
                float tm = sa[t2][0][0];
                #pragma unroll
                for (int mt = 0; mt < 4; ++mt)
                    #pragma unroll
                    for (int rr = 0; rr < 4; ++rr) tm = fmaxf(tm, sa[t2][mt][rr]);
                tm = fmaxf(tm, __shfl_xor(tm, 16));
                tm = fmaxf(tm, __shfl_xor(tm, 32));
                if (__any(tm > m_[t2] + 8.0f)) {
                    float mnew = fmaxf(m_[t2], tm);
                    float al = exp2f(m_[t2] - mnew);
                    m_[t2] = mnew;
                    lsum[t2] *= al;
                    #pragma unroll
                    for (int rr = 0; rr < 4; ++rr) {
                        float alr = __shfl(al, g * 4 + rr);
                        #pragma unroll
                        for (int dt = 0; dt < 8; ++dt) o[t2][dt][rr] *= alr;
                    }
                }
                float mref = m_[t2];
                float ls = 0.f;
                int prow = t2 * 16 + qc;
                int pswz = (prow & 7) << 4;
                #pragma unroll
                for (int mt = 0; mt < 4; ++mt) {
                    f32x4 p;
                    #pragma unroll
                    for (int rr = 0; rr < 4; ++rr)
                        p[rr] = exp2f(sa[t2][mt][rr] - mref);
                    ls += (p[0] + p[1]) + (p[2] + p[3]);
                    u32x2 pw;
                    pw[0] = pk2(p[0], p[1]);
                    pw[1] = pk2(p[2], p[3]);
                    *(u32x2*)(PsB + ((prow * 128 + mt * 32 + g * 8) ^ pswz)) = pw;
                }
                lsum[t2] += ls;
            }
            bf16x8 ap[2][2];
            #pragma unroll
            for (int t2 = 0; t2 < 2; ++t2) {
                int prow = t2 * 16 + qc;
                int pswz = (prow & 7) << 4;
                #pragma unroll
                for (int c = 0; c < 2; ++c)
                    ap[t2][c] = *(const bf16x8*)(PsB + ((prow * 128 + c * 64 + g * 16) ^ pswz));
            }
            #pragma unroll
            for (int dt = 0; dt < 8; ++dt) {
                int d = dt * 16 + qc;
                #pragma unroll
                for (int c = 0; c < 2; ++c) {
                    int js = (c * 4 + g) ^ (d & 7);
                    bf16x8 bfv = *(const bf16x8*)((const char*)Vt + d * 128 + js * 16);
                    #pragma unroll
                    for (int t2 = 0; t2 < 2; ++t2)
                        o[t2][dt] = __builtin_amdgcn_mfma_f32_16x16x32_bf16(
                            ap[t2][c], bfv, o[t2][dt], 0, 0, 0);
                }
            }
        }
    }

    float inv_[2][4];
    #pragma unroll
    for (int t2 = 0; t2 < 2; ++t2) {
        float L = lsum[t2];
        L += __shfl_xor(L, 16);
        L += __shfl_xor(L, 32);
        #pragma unroll
        for (int rr = 0; rr < 4; ++rr) {
            float Lr = __shfl(L, g * 4 + rr);
            inv_[t2][rr] = 1.0f / Lr;
        }
    }
    bool needvm = (qw0 + 32 > len);
    float vmv[8];
    #pragma unroll
    for (int dt = 0; dt < 8; ++dt)
        vmv[dt] = needvm ? vmean[bh * Dd + dt * 16 + qc] : 0.f;
    #pragma unroll
    for (int t2 = 0; t2 < 2; ++t2)
        #pragma unroll
        for (int rr = 0; rr < 4; ++rr) {
            int rowg = qw0 + t2 * 16 + g * 4 + rr;
            float* orow = Og + ((size_t)bh * Ss + rowg) * Dd + qc;
            #pragma unroll
            for (int dt = 0; dt < 8; ++dt) {
                float val = o[t2][dt][rr] * inv_[t2][rr];
                if (rowg >= len) val = vmv[dt];
                orow[dt * 16] = val;
            }
        }
}

extern "C" void kernel_launch(void* const* d_in, const int* in_sizes, int n_in,
                              void* d_out, int out_size, void* d_ws, size_t ws_size,
                              hipStream_t stream) {
    const float* q  = (const float*)d_in[0];
    const float* k  = (const float*)d_in[1];
    const float* v  = (const float*)d_in[2];
    const int*   sl = (const int*)d_in[3];
    float* out = (float*)d_out;

    const size_t nElem = (size_t)Bb * Hh * Ss * Dd;            // 16,777,216
    const size_t need0 = nElem * 2 * 2 + 2048 * Dd * 4 + 64 * Dd * 4;

    if (ws_size >= need0) {
        short* Kbf  = (short*)d_ws;
        short* Vf   = Kbf + nElem;
        float* part = (float*)(Vf + nElem);
        float* vm   = part + 2048 * Dd;
        cvtk_kernel<<<dim3(8192), dim3(256), 0, stream>>>(k, Kbf);
        cvtvf_kernel<<<dim3(2048), dim3(256), 0, stream>>>(v, Vf, part);
        vcomb_kernel<<<dim3(Bb * Hh), dim3(128), 0, stream>>>(part, vm, 32);
        attn3_kernel<<<dim3(1024), dim3(256), 0, stream>>>(q, Kbf, Vf, sl, vm, out);
    } else {
        float* part = (float*)d_ws;
        float* vm   = part + 512 * Dd;
        vpart_kernel<<<dim3(512), dim3(256), 0, stream>>>(v, part);
        vcomb_kernel<<<dim3(Bb * Hh), dim3(128), 0, stream>>>(part, vm, 8);
        attn_fb_kernel<<<dim3(1024), dim3(256), 0, stream>>>(q, k, v, sl, vm, out);
    }
}

// Round 9
// 250.025 us; speedup vs baseline: 1.2014x; 1.2014x over previous
//
#include <hip/hip_runtime.h>
#include <hip/hip_bf16.h>

#define Bb   4
#define Hh   16
#define Ss   2048
#define Dd   128
#define QBLK 128
#define KVB  32

typedef __attribute__((ext_vector_type(8))) short bf16x8;
typedef __attribute__((ext_vector_type(4))) float f32x4;
typedef __attribute__((ext_vector_type(4))) float fvec4;
typedef __attribute__((ext_vector_type(2))) unsigned u32x2;
typedef __attribute__((ext_vector_type(4))) unsigned u32x4;

__device__ __forceinline__ unsigned pk2(float a, float b) {
    __hip_bfloat162 h = __float22bfloat162_rn(make_float2(a, b));
    unsigned u; __builtin_memcpy(&u, &h, 4); return u;
}

typedef const __attribute__((address_space(1))) char* gas_t;
typedef __attribute__((address_space(3))) char* las_t;
__device__ __forceinline__ void gld16(const void* g, void* l) {
    __builtin_amdgcn_global_load_lds((gas_t)g, (las_t)l, 16, 0, 0);
}

// ---------- prepass A: K fp32 [bh][s][d] -> A-fragment tiles (32-row KV tiles) ----------
// Kf[bh][kt(64)][mt(2)][kc(4)][lane(64)][8bf16]; lane=(g<<4)|qc holds
//   K[s=kt*32+mt*16+qc][d=kc*32+g*8+j]  (8 KB per tile)
__global__ __launch_bounds__(256) void cvtkf_kernel(const float* __restrict__ K,
                                                    short* __restrict__ Kf) {
    const int bh = blockIdx.x >> 5, ch = blockIdx.x & 31;   // 64 rows per block
    const int tid = threadIdx.x;
    const float* Kb = K + ((size_t)bh * Ss + ch * 64) * Dd;
    short* out = Kf + ((size_t)(bh * 64 + ch * 2)) * 4096;  // 2 tiles x 4096 shorts
    #pragma unroll
    for (int i = 0; i < 4; ++i) {
        int c = tid + 256 * i;                              // [0,1024) 16B chunks
        int kt = c >> 9, r = c & 511;
        int mt = r >> 8, kc = (r >> 6) & 3, l = r & 63;
        int g = l >> 4, qc = l & 15;
        const fvec4* p = (const fvec4*)(Kb + (size_t)(kt * 32 + mt * 16 + qc) * Dd
                                        + kc * 32 + g * 8);
        fvec4 a = p[0], b = p[1];
        u32x4 u;
        u[0] = pk2(a[0], a[1]); u[1] = pk2(a[2], a[3]);
        u[2] = pk2(b[0], b[1]); u[3] = pk2(b[2], b[3]);
        *(u32x4*)(out + c * 8) = u;
    }
}

// ---------- prepass B: V fp32 [bh][s][d] -> B-fragment tiles + partial col sums ----------
// Vf[bh][kt(64)][dt(8)][lane(64)][8bf16]; lane holds V[s=kt*32+g*8+j][d=dt*16+qc]
__global__ __launch_bounds__(256) void cvtvf_kernel(const float* __restrict__ V,
                                                    short* __restrict__ Vf,
                                                    float* __restrict__ part) {
    __shared__ float bins[128];
    const int bh = blockIdx.x >> 5, ch = blockIdx.x & 31;
    const int tid = threadIdx.x;
    if (tid < 128) bins[tid] = 0.f;
    __syncthreads();
    const float* Vb = V + ((size_t)bh * Ss + ch * 64) * Dd;
    short* out = Vf + ((size_t)(bh * 64 + ch * 2)) * 4096;
    #pragma unroll
    for (int i = 0; i < 4; ++i) {
        int c = tid + 256 * i;
        int kt = c >> 9, r = c & 511;
        int dt = r >> 6, l = r & 63;
        int g = l >> 4, qc = l & 15;
        int d = dt * 16 + qc;
        const float* src = Vb + (size_t)(kt * 32 + g * 8) * Dd + d;
        float v[8]; float s = 0.f;
        #pragma unroll
        for (int j = 0; j < 8; ++j) { v[j] = src[(size_t)j * Dd]; s += v[j]; }
        atomicAdd(&bins[d], s);
        u32x4 u;
        u[0] = pk2(v[0], v[1]); u[1] = pk2(v[2], v[3]);
        u[2] = pk2(v[4], v[5]); u[3] = pk2(v[6], v[7]);
        *(u32x4*)(out + c * 8) = u;
    }
    __syncthreads();
    if (tid < 128) part[(size_t)blockIdx.x * Dd + tid] = bins[tid];
}

// ---------- fallback partial V sums ----------
__global__ __launch_bounds__(256) void vpart_kernel(const float* __restrict__ V,
                                                    float* __restrict__ part) {
    int blk = blockIdx.x, bh = blk >> 3, ch = blk & 7;
    int tid = threadIdx.x, d4 = tid & 31, rg = tid >> 5;
    const fvec4* p = (const fvec4*)(V + ((size_t)bh * Ss + ch * 256) * Dd) + d4;
    fvec4 s = {0.f, 0.f, 0.f, 0.f};
    for (int rr = 0; rr < 32; ++rr) s += p[(size_t)(rg * 32 + rr) * 32];
    __shared__ fvec4 red[256];
    red[tid] = s;
    __syncthreads();
    for (int off = 128; off >= 32; off >>= 1) {
        if (tid < off) red[tid] += red[tid + off];
        __syncthreads();
    }
    if (tid < 32) ((fvec4*)(part + (size_t)blk * Dd))[tid] = red[tid];
}

// ---------- combine partials -> vmean ----------
__global__ __launch_bounds__(128) void vcomb_kernel(const float* __restrict__ part,
                                                    float* __restrict__ vm, int nch) {
    int bh = blockIdx.x, d = threadIdx.x;
    float s = 0.f;
    for (int c = 0; c < nch; ++c) s += part[(size_t)(bh * nch + c) * Dd + d];
    vm[bh * Dd + d] = s * (1.0f / 2048.0f);
}

// ====== flash attention: KVB=32, fragment-ordered DMA dbuf, 40KB LDS, 4 blk/CU ======
__global__ __launch_bounds__(256, 4) void attn4_kernel(
    const float* __restrict__ Qg, const short* __restrict__ Kf,
    const short* __restrict__ Vf, const int* __restrict__ slen,
    const float* __restrict__ vmean, float* __restrict__ Og)
{
    __shared__ __align__(16) short Ks[2][2048];        // 4KB per buf (first half of K tile)
    __shared__ __align__(16) short Ks2[2][2048];       // 4KB per buf (second half)
    __shared__ __align__(16) short Vs[2][2048];
    __shared__ __align__(16) short Vs2[2][2048];
    __shared__ __align__(16) short Ps[4096];           // 4 waves x 2KB

    const int bid = blockIdx.x;
    const int qslot = bid >> 6, r = bid & 63;
    const int qt = 15 - qslot;                         // deepest q-tiles first
    const int b  = (r >> 3) & 3;                       // every batch on every XCD
    const int h  = (r & 7) | ((r >> 5) << 3);
    const int bh = b * 16 + h;                         // (b,h)'s q-tiles share XCD
    const int len = slen[b];
    const int q0 = qt * QBLK;
    const int tid = threadIdx.x;

    if (q0 >= len) {                                   // fully-invalid: rows = mean(V)
        const fvec4* vm4 = (const fvec4*)(vmean + bh * Dd);
        fvec4 val = vm4[tid & 31];
        float* ob = Og + ((size_t)bh * Ss + q0) * Dd;
        int r0 = tid >> 5;
        #pragma unroll
        for (int i = 0; i < 16; ++i)
            ((fvec4*)(ob + (size_t)(r0 + 8 * i) * Dd))[tid & 31] = val;
        return;
    }

    const int w = tid >> 6, lane = tid & 63;
    const int g = lane >> 4, qc = lane & 15;
    const int qw0 = q0 + w * 32;
    const bool wave_active = (qw0 < len);
    const int lo16 = lane * 16;

    const int kv_end   = min(q0 + QBLK, len);
    const int kv_end_w = min(qw0 + 32, kv_end);
    const int nt = (kv_end + KVB - 1) >> 5;

    const char* KbhB = (const char*)Kf + (size_t)bh * 524288;
    const char* VbhB = (const char*)Vf + (size_t)bh * 524288;

    // each tile = 8KB K frag + 8KB V frag, linear; wave w copies its 2KB quarter
    #define GISSUE(tile_, buf_) do {                                                   \
        const char* kb_ = KbhB + (size_t)(tile_) * 8192 + w * 2048;                    \
        const char* vb_ = VbhB + (size_t)(tile_) * 8192 + w * 2048;                    \
        char* kd_ = (w < 2) ? (char*)Ks[buf_] : (char*)Ks2[buf_];                      \
        char* vd_ = (w < 2) ? (char*)Vs[buf_] : (char*)Vs2[buf_];                      \
        kd_ += (w & 1) * 2048;                                                         \
        vd_ += (w & 1) * 2048;                                                         \
        gld16(kb_ + lo16, kd_);                                                        \
        gld16(kb_ + 1024 + lo16, kd_ + 1024);                                          \
        gld16(vb_ + lo16, vd_);                                                        \
        gld16(vb_ + 1024 + lo16, vd_ + 1024);                                          \
    } while (0)

    GISSUE(0, 0);                                      // tile-0 DMA under Q load

    const float SC = 0.12752870368768582f;             // log2(e)/sqrt(128)
    bf16x8 qf[2][4];
    #pragma unroll
    for (int t2 = 0; t2 < 2; ++t2) {
        const float* qrow = Qg + ((size_t)bh * Ss + (qw0 + 16 * t2 + qc)) * Dd;
        #pragma unroll
        for (int kc = 0; kc < 4; ++kc) {
            const fvec4* p = (const fvec4*)(qrow + kc * 32 + g * 8);
            fvec4 a = p[0], bv = p[1];
            unsigned* fu = (unsigned*)&qf[t2][kc];
            fu[0] = pk2(a[0] * SC, a[1] * SC);
            fu[1] = pk2(a[2] * SC, a[3] * SC);
            fu[2] = pk2(bv[0] * SC, bv[1] * SC);
            fu[3] = pk2(bv[2] * SC, bv[3] * SC);
        }
    }

    asm volatile("s_waitcnt vmcnt(0)" ::: "memory");
    __syncthreads();

    f32x4 o[2][8];
    #pragma unroll
    for (int t2 = 0; t2 < 2; ++t2)
        #pragma unroll
        for (int dt = 0; dt < 8; ++dt) o[t2][dt] = (f32x4){0.f, 0.f, 0.f, 0.f};
    float m_[2]   = {-3e38f, -3e38f};
    float lsum[2] = {0.f, 0.f};

    char* PsB = (char*)Ps + w * 2048;                  // FIX (R8 bug): 2KB per wave, not 1KB
    const int sw0 = (qc ^ (qc >> 2)) & 3;              // Ps granule swizzle (prow&15==qc)

    for (int t = 0; t < nt; ++t) {
        const int kv0 = t * KVB;
        const int cur = t & 1;
        const bool pre = (t + 1 < nt);
        const bool active = wave_active && (kv0 < kv_end_w);

        if (pre) GISSUE(t + 1, cur ^ 1);               // next-tile DMA under compute

        if (active) {
            const char* KsA = (const char*)Ks[cur];
            const char* KsB2 = (const char*)Ks2[cur];
            const char* VsA = (const char*)Vs[cur];
            const char* VsB2 = (const char*)Vs2[cur];

            // ---- QK^T: A-frags linear from LDS ----
            f32x4 sa[2][2];
            #pragma unroll
            for (int t2 = 0; t2 < 2; ++t2)
                #pragma unroll
                for (int mt = 0; mt < 2; ++mt) sa[t2][mt] = (f32x4){0.f, 0.f, 0.f, 0.f};
            __builtin_amdgcn_s_setprio(1);
            #pragma unroll
            for (int mt = 0; mt < 2; ++mt) {
                bf16x8 kf[4];
                #pragma unroll
                for (int kc = 0; kc < 4; ++kc) {
                    int chunk = mt * 4 + kc;           // [0,8) -> 8KB across Ks/Ks2
                    const char* base = (chunk < 4) ? KsA : KsB2;
                    kf[kc] = *(const bf16x8*)(base + (chunk & 3) * 1024 + lo16);
                }
                #pragma unroll
                for (int t2 = 0; t2 < 2; ++t2)
                    #pragma unroll
                    for (int kc = 0; kc < 4; ++kc)
                        sa[t2][mt] = __builtin_amdgcn_mfma_f32_16x16x32_bf16(
                            kf[kc], qf[t2][kc], sa[t2][mt], 0, 0, 0);
            }
            __builtin_amdgcn_s_setprio(0);

            // ---- mask + online softmax (defer-max) ----
            #pragma unroll
            for (int t2 = 0; t2 < 2; ++t2) {
                const int qrow = qw0 + 16 * t2 + qc;
                const bool full = (kv0 + KVB - 1) <= (qw0 + 16 * t2);
                if (!full) {
                    #pragma unroll
                    for (int mt = 0; mt < 2; ++mt)
                        #pragma unroll
                        for (int rr = 0; rr < 4; ++rr) {
                            int kk = kv0 + mt * 16 + g * 4 + rr;
                            if (kk > qrow) sa[t2][mt][rr] = -3e38f;
                        }
                }
                float tm = fmaxf(
                    fmaxf(fmaxf(sa[t2][0][0], sa[t2][0][1]), fmaxf(sa[t2][0][2], sa[t2][0][3])),
                    fmaxf(fmaxf(sa[t2][1][0], sa[t2][1][1]), fmaxf(sa[t2][1][2], sa[t2][1][3])));
                tm = fmaxf(tm, __shfl_xor(tm, 16));
                tm = fmaxf(tm, __shfl_xor(tm, 32));
                if (__any(tm > m_[t2] + 8.0f)) {
                    float mnew = fmaxf(m_[t2], tm);
                    float al = exp2f(m_[t2] - mnew);
                    m_[t2] = mnew;
                    lsum[t2] *= al;
                    #pragma unroll
                    for (int rr = 0; rr < 4; ++rr) {
                        float alr = __shfl(al, g * 4 + rr);
                        #pragma unroll
                        for (int dt = 0; dt < 8; ++dt) o[t2][dt][rr] *= alr;
                    }
                }
                float mref = m_[t2];
                float ls = 0.f;
                int prow = t2 * 16 + qc;
                #pragma unroll
                for (int mt = 0; mt < 2; ++mt) {
                    f32x4 p;
                    #pragma unroll
                    for (int rr = 0; rr < 4; ++rr)
                        p[rr] = exp2f(sa[t2][mt][rr] - mref);
                    ls += (p[0] + p[1]) + (p[2] + p[3]);
                    u32x2 pw;
                    pw[0] = pk2(p[0], p[1]);
                    pw[1] = pk2(p[2], p[3]);
                    int bo = prow * 64 + (((mt * 2 + (g >> 1)) ^ sw0) * 16) + (g & 1) * 8;
                    *(u32x2*)(PsB + bo) = pw;
                }
                lsum[t2] += ls;
            }

            // ---- PV: P-frag from Ps, B-frags linear from LDS ----
            bf16x8 ap[2];
            #pragma unroll
            for (int t2 = 0; t2 < 2; ++t2) {
                int prow = t2 * 16 + qc;
                ap[t2] = *(const bf16x8*)(PsB + prow * 64 + ((g ^ sw0) * 16));
            }
            __builtin_amdgcn_s_setprio(1);
            #pragma unroll
            for (int dt = 0; dt < 8; ++dt) {
                const char* base = (dt < 4) ? VsA : VsB2;
                bf16x8 bfv = *(const bf16x8*)(base + (dt & 3) * 1024 + lo16);
                #pragma unroll
                for (int t2 = 0; t2 < 2; ++t2)
                    o[t2][dt] = __builtin_amdgcn_mfma_f32_16x16x32_bf16(
                        ap[t2], bfv, o[t2][dt], 0, 0, 0);
            }
            __builtin_amdgcn_s_setprio(0);
        }

        asm volatile("s_waitcnt vmcnt(0)" ::: "memory");
        __syncthreads();
    }
    #undef GISSUE

    // ---- epilogue ----
    float inv_[2][4];
    #pragma unroll
    for (int t2 = 0; t2 < 2; ++t2) {
        float L = lsum[t2];
        L += __shfl_xor(L, 16);
        L += __shfl_xor(L, 32);
        #pragma unroll
        for (int rr = 0; rr < 4; ++rr) {
            float Lr = __shfl(L, g * 4 + rr);
            inv_[t2][rr] = 1.0f / Lr;
        }
    }
    bool needvm = (qw0 + 32 > len);
    float vmv[8];
    #pragma unroll
    for (int dt = 0; dt < 8; ++dt)
        vmv[dt] = needvm ? vmean[bh * Dd + dt * 16 + qc] : 0.f;
    #pragma unroll
    for (int t2 = 0; t2 < 2; ++t2)
        #pragma unroll
        for (int rr = 0; rr < 4; ++rr) {
            int rowg = qw0 + t2 * 16 + g * 4 + rr;
            float* orow = Og + ((size_t)bh * Ss + rowg) * Dd + qc;
            #pragma unroll
            for (int dt = 0; dt < 8; ++dt) {
                float val = o[t2][dt][rr] * inv_[t2][rr];
                if (rowg >= len) val = vmv[dt];
                orow[dt * 16] = val;
            }
        }
}

// ================= fallback (ws too small): 4-wave in-kernel cvt (R4-proven) ======
__global__ __launch_bounds__(256, 2) void attn_fb_kernel(
    const float* __restrict__ Qg, const float* __restrict__ Kg,
    const float* __restrict__ Vg, const int* __restrict__ slen,
    const float* __restrict__ vmean, float* __restrict__ Og)
{
    __shared__ __align__(16) short Ks[64 * Dd];
    __shared__ __align__(16) short Vt[Dd * 64];
    __shared__ __align__(16) short Ps[4 * 32 * 64];

    const int bid = blockIdx.x;
    const int qslot = bid >> 6, r = bid & 63;
    const int qt = 15 - qslot;
    const int b  = (r >> 3) & 3;
    const int h  = (r & 7) | ((r >> 5) << 3);
    const int bh = b * 16 + h;
    const int len = slen[b];
    const int q0 = qt * QBLK;
    const int tid = threadIdx.x;

    if (q0 >= len) {
        const fvec4* vm4 = (const fvec4*)(vmean + bh * Dd);
        fvec4 val = vm4[tid & 31];
        float* ob = Og + ((size_t)bh * Ss + q0) * Dd;
        int r0 = tid >> 5;
        #pragma unroll
        for (int i = 0; i < 16; ++i)
            ((fvec4*)(ob + (size_t)(r0 + 8 * i) * Dd))[tid & 31] = val;
        return;
    }

    const int w = tid >> 6, lane = tid & 63;
    const int g = lane >> 4, qc = lane & 15;
    const int qw0 = q0 + w * 32;
    const bool wave_active = (qw0 < len);

    const int kv_end   = min(q0 + QBLK, len);
    const int kv_end_w = min(qw0 + 32, kv_end);
    const int nt = (kv_end + 63) >> 6;

    const float SC = 0.12752870368768582f;
    bf16x8 qf[2][4];
    #pragma unroll
    for (int t2 = 0; t2 < 2; ++t2) {
        const float* qrow = Qg + ((size_t)bh * Ss + (qw0 + 16 * t2 + qc)) * Dd;
        #pragma unroll
        for (int kc = 0; kc < 4; ++kc) {
            const fvec4* p = (const fvec4*)(qrow + kc * 32 + g * 8);
            fvec4 a = p[0], bv = p[1];
            unsigned* fu = (unsigned*)&qf[t2][kc];
            fu[0] = pk2(a[0] * SC, a[1] * SC);
            fu[1] = pk2(a[2] * SC, a[3] * SC);
            fu[2] = pk2(bv[0] * SC, bv[1] * SC);
            fu[3] = pk2(bv[2] * SC, bv[3] * SC);
        }
    }

    f32x4 o[2][8];
    #pragma unroll
    for (int t2 = 0; t2 < 2; ++t2)
        #pragma unroll
        for (int dt = 0; dt < 8; ++dt) o[t2][dt] = (f32x4){0.f, 0.f, 0.f, 0.f};
    float m_[2]   = {-3e38f, -3e38f};
    float lsum[2] = {0.f, 0.f};
    char* PsB = (char*)Ps + w * 4096;

    for (int t = 0; t < nt; ++t) {
        const int kv0 = t * 64;
        const bool active = wave_active && (kv0 < kv_end_w);
        __syncthreads();
        {
            const fvec4* sk = (const fvec4*)(Kg + ((size_t)bh * Ss + kv0) * Dd);
            #pragma unroll
            for (int i = 0; i < 8; ++i) {
                int f = tid + 256 * i;
                int kr = f >> 5, d4 = f & 31;
                fvec4 v = sk[(size_t)kr * 32 + d4];
                u32x2 pr; pr[0] = pk2(v[0], v[1]); pr[1] = pk2(v[2], v[3]);
                int j = d4 >> 1;
                int js = (j & 8) | ((j & 7) ^ (kr & 7));
                *(u32x2*)((char*)Ks + kr * 256 + js * 16 + (d4 & 1) * 8) = pr;
            }
            const float* sv = Vg + ((size_t)bh * Ss + kv0) * Dd;
            #pragma unroll
            for (int i = 0; i < 2; ++i) {
                int idx = tid + 256 * i;
                int dt4 = idx & 31, kt4 = idx >> 5;
                fvec4 vv[4];
                #pragma unroll
                for (int jj = 0; jj < 4; ++jj)
                    vv[jj] = ((const fvec4*)(sv + (size_t)(kt4 * 4 + jj) * Dd))[dt4];
                #pragma unroll
                for (int jj = 0; jj < 4; ++jj) {
                    int d = dt4 * 4 + jj;
                    u32x2 pr;
                    pr[0] = pk2(vv[0][jj], vv[1][jj]);
                    pr[1] = pk2(vv[2][jj], vv[3][jj]);
                    int bo = d * 128 + ((kt4 >> 1) ^ (d & 7)) * 16 + (kt4 & 1) * 8;
                    *(u32x2*)((char*)Vt + bo) = pr;
                }
            }
        }
        __syncthreads();

        if (active) {
            f32x4 sa[2][4];
            #pragma unroll
            for (int t2 = 0; t2 < 2; ++t2)
                #pragma unroll
                for (int mt = 0; mt < 4; ++mt) sa[t2][mt] = (f32x4){0.f, 0.f, 0.f, 0.f};
            #pragma unroll
            for (int mt = 0; mt < 4; ++mt) {
                int row = mt * 16 + qc;
                bf16x8 kf[4];
                #pragma unroll
                for (int kc = 0; kc < 4; ++kc) {
                    int jb = kc * 4 + g;
                    int js = (jb & 8) | ((jb & 7) ^ (row & 7));
                    kf[kc] = *(const bf16x8*)((const char*)Ks + row * 256 + js * 16);
                }
                #pragma unroll
                for (int t2 = 0; t2 < 2; ++t2)
                    #pragma unroll
                    for (int kc = 0; kc < 4; ++kc)
                        sa[t2][mt] = __builtin_amdgcn_mfma_f32_16x16x32_bf16(
                            kf[kc], qf[t2][kc], sa[t2][mt], 0, 0, 0);
            }
            #pragma unroll
            for (int t2 = 0; t2 < 2; ++t2) {
                const int qrow = qw0 + 16 * t2 + qc;
                const bool full = (kv0 + 63) <= (qw0 + 16 * t2);
                if (!full) {
                    #pragma unroll
                    for (int mt = 0; mt < 4; ++mt)
                        #pragma unroll
                        for (int rr = 0; rr < 4; ++rr) {
                            int kk = kv0 + mt * 16 + g * 4 + rr;
                            if (kk > qrow) sa[t2][mt][rr] = -3e38f;
                        }
                }
                float tm = sa[t2][0][0];
                #pragma unroll
                for (int mt = 0; mt < 4; ++mt)
                    #pragma unroll
                    for (int rr = 0; rr < 4; ++rr) tm = fmaxf(tm, sa[t2][mt][rr]);
                tm = fmaxf(tm, __shfl_xor(tm, 16));
                tm = fmaxf(tm, __shfl_xor(tm, 32));
                if (__any(tm > m_[t2] + 8.0f)) {
                    float mnew = fmaxf(m_[t2], tm);
                    float al = exp2f(m_[t2] - mnew);
                    m_[t2] = mnew;
                    lsum[t2] *= al;
                    #pragma unroll
                    for (int rr = 0; rr < 4; ++rr) {
                        float alr = __shfl(al, g * 4 + rr);
                        #pragma unroll
                        for (int dt = 0; dt < 8; ++dt) o[t2][dt][rr] *= alr;
                    }
                }
                float mref = m_[t2];
                float ls = 0.f;
                int prow = t2 * 16 + qc;
                int pswz = (prow & 7) << 4;
                #pragma unroll
                for (int mt = 0; mt < 4; ++mt) {
                    f32x4 p;
                    #pragma unroll
                    for (int rr = 0; rr < 4; ++rr)
                        p[rr] = exp2f(sa[t2][mt][rr] - mref);
                    ls += (p[0] + p[1]) + (p[2] + p[3]);
                    u32x2 pw;
                    pw[0] = pk2(p[0], p[1]);
                    pw[1] = pk2(p[2], p[3]);
                    *(u32x2*)(PsB + ((prow * 128 + mt * 32 + g * 8) ^ pswz)) = pw;
                }
                lsum[t2] += ls;
            }
            bf16x8 ap[2][2];
            #pragma unroll
            for (int t2 = 0; t2 < 2; ++t2) {
                int prow = t2 * 16 + qc;
                int pswz = (prow & 7) << 4;
                #pragma unroll
                for (int c = 0; c < 2; ++c)
                    ap[t2][c] = *(const bf16x8*)(PsB + ((prow * 128 + c * 64 + g * 16) ^ pswz));
            }
            #pragma unroll
            for (int dt = 0; dt < 8; ++dt) {
                int d = dt * 16 + qc;
                #pragma unroll
                for (int c = 0; c < 2; ++c) {
                    int js = (c * 4 + g) ^ (d & 7);
                    bf16x8 bfv = *(const bf16x8*)((const char*)Vt + d * 128 + js * 16);
                    #pragma unroll
                    for (int t2 = 0; t2 < 2; ++t2)
                        o[t2][dt] = __builtin_amdgcn_mfma_f32_16x16x32_bf16(
                            ap[t2][c], bfv, o[t2][dt], 0, 0, 0);
                }
            }
        }
    }

    float inv_[2][4];
    #pragma unroll
    for (int t2 = 0; t2 < 2; ++t2) {
        float L = lsum[t2];
        L += __shfl_xor(L, 16);
        L += __shfl_xor(L, 32);
        #pragma unroll
        for (int rr = 0; rr < 4; ++rr) {
            float Lr = __shfl(L, g * 4 + rr);
            inv_[t2][rr] = 1.0f / Lr;
        }
    }
    bool needvm = (qw0 + 32 > len);
    float vmv[8];
    #pragma unroll
    for (int dt = 0; dt < 8; ++dt)
        vmv[dt] = needvm ? vmean[bh * Dd + dt * 16 + qc] : 0.f;
    #pragma unroll
    for (int t2 = 0; t2 < 2; ++t2)
        #pragma unroll
        for (int rr = 0; rr < 4; ++rr) {
            int rowg = qw0 + t2 * 16 + g * 4 + rr;
            float* orow = Og + ((size_t)bh * Ss + rowg) * Dd + qc;
            #pragma unroll
            for (int dt = 0; dt < 8; ++dt) {
                float val = o[t2][dt][rr] * inv_[t2][rr];
                if (rowg >= len) val = vmv[dt];
                orow[dt * 16] = val;
            }
        }
}

extern "C" void kernel_launch(void* const* d_in, const int* in_sizes, int n_in,
                              void* d_out, int out_size, void* d_ws, size_t ws_size,
                              hipStream_t stream) {
    const float* q  = (const float*)d_in[0];
    const float* k  = (const float*)d_in[1];
    const float* v  = (const float*)d_in[2];
    const int*   sl = (const int*)d_in[3];
    float* out = (float*)d_out;

    const size_t nElem = (size_t)Bb * Hh * Ss * Dd;            // 16,777,216
    const size_t need0 = nElem * 2 * 2 + 2048 * Dd * 4 + 64 * Dd * 4;

    if (ws_size >= need0) {
        short* Kf   = (short*)d_ws;
        short* Vf   = Kf + nElem;
        float* part = (float*)(Vf + nElem);
        float* vm   = part + 2048 * Dd;
        cvtkf_kernel<<<dim3(2048), dim3(256), 0, stream>>>(k, Kf);
        cvtvf_kernel<<<dim3(2048), dim3(256), 0, stream>>>(v, Vf, part);
        vcomb_kernel<<<dim3(Bb * Hh), dim3(128), 0, stream>>>(part, vm, 32);
        attn4_kernel<<<dim3(1024), dim3(256), 0, stream>>>(q, Kf, Vf, sl, vm, out);
    } else {
        float* part = (float*)d_ws;
        float* vm   = part + 512 * Dd;
        vpart_kernel<<<dim3(512), dim3(256), 0, stream>>>(v, part);
        vcomb_kernel<<<dim3(Bb * Hh), dim3(128), 0, stream>>>(part, vm, 8);
        attn_fb_kernel<<<dim3(1024), dim3(256), 0, stream>>>(q, k, v, sl, vm, out);
    }
}

// Round 10
// 149.952 us; speedup vs baseline: 2.0032x; 1.6674x over previous
//
#include <hip/hip_runtime.h>
#include <hip/hip_bf16.h>

#define Bb   4
#define Hh   16
#define Ss   2048
#define Dd   128
#define QBLK 128
#define KVB  32

typedef __attribute__((ext_vector_type(8))) short bf16x8;
typedef __attribute__((ext_vector_type(4))) float f32x4;
typedef __attribute__((ext_vector_type(4))) float fvec4;
typedef __attribute__((ext_vector_type(2))) unsigned u32x2;
typedef __attribute__((ext_vector_type(4))) unsigned u32x4;

__device__ __forceinline__ unsigned pk2(float a, float b) {
    __hip_bfloat162 h = __float22bfloat162_rn(make_float2(a, b));
    unsigned u; __builtin_memcpy(&u, &h, 4); return u;
}

typedef const __attribute__((address_space(1))) char* gas_t;
typedef __attribute__((address_space(3))) char* las_t;
__device__ __forceinline__ void gld16(const void* g, void* l) {
    __builtin_amdgcn_global_load_lds((gas_t)g, (las_t)l, 16, 0, 0);
}

// ---------- prepass A: K fp32 [bh][s][d] -> A-fragment tiles (32-row KV tiles) ----------
// Kf[bh][kt(64)][mt(2)][kc(4)][lane(64)][8bf16]; lane=(g<<4)|qc holds
//   K[s=kt*32+mt*16+qc][d=kc*32+g*8+j]  (8 KB per tile)
__global__ __launch_bounds__(256) void cvtkf_kernel(const float* __restrict__ K,
                                                    short* __restrict__ Kf) {
    const int bh = blockIdx.x >> 5, ch = blockIdx.x & 31;   // 64 rows per block
    const int tid = threadIdx.x;
    const float* Kb = K + ((size_t)bh * Ss + ch * 64) * Dd;
    short* out = Kf + ((size_t)(bh * 64 + ch * 2)) * 4096;  // 2 tiles x 4096 shorts
    #pragma unroll
    for (int i = 0; i < 4; ++i) {
        int c = tid + 256 * i;                              // [0,1024) 16B chunks
        int kt = c >> 9, r = c & 511;
        int mt = r >> 8, kc = (r >> 6) & 3, l = r & 63;
        int g = l >> 4, qc = l & 15;
        const fvec4* p = (const fvec4*)(Kb + (size_t)(kt * 32 + mt * 16 + qc) * Dd
                                        + kc * 32 + g * 8);
        fvec4 a = p[0], b = p[1];
        u32x4 u;
        u[0] = pk2(a[0], a[1]); u[1] = pk2(a[2], a[3]);
        u[2] = pk2(b[0], b[1]); u[3] = pk2(b[2], b[3]);
        *(u32x4*)(out + c * 8) = u;
    }
}

// ---------- prepass B: V fp32 [bh][s][d] -> B-fragment tiles + partial col sums ----------
// Vf[bh][kt(64)][dt(8)][lane(64)][8bf16]; lane holds V[s=kt*32+g*8+j][d=dt*16+qc]
__global__ __launch_bounds__(256) void cvtvf_kernel(const float* __restrict__ V,
                                                    short* __restrict__ Vf,
                                                    float* __restrict__ part) {
    __shared__ float bins[128];
    const int bh = blockIdx.x >> 5, ch = blockIdx.x & 31;
    const int tid = threadIdx.x;
    if (tid < 128) bins[tid] = 0.f;
    __syncthreads();
    const float* Vb = V + ((size_t)bh * Ss + ch * 64) * Dd;
    short* out = Vf + ((size_t)(bh * 64 + ch * 2)) * 4096;
    #pragma unroll
    for (int i = 0; i < 4; ++i) {
        int c = tid + 256 * i;
        int kt = c >> 9, r = c & 511;
        int dt = r >> 6, l = r & 63;
        int g = l >> 4, qc = l & 15;
        int d = dt * 16 + qc;
        const float* src = Vb + (size_t)(kt * 32 + g * 8) * Dd + d;
        float v[8]; float s = 0.f;
        #pragma unroll
        for (int j = 0; j < 8; ++j) { v[j] = src[(size_t)j * Dd]; s += v[j]; }
        atomicAdd(&bins[d], s);
        u32x4 u;
        u[0] = pk2(v[0], v[1]); u[1] = pk2(v[2], v[3]);
        u[2] = pk2(v[4], v[5]); u[3] = pk2(v[6], v[7]);
        *(u32x4*)(out + c * 8) = u;
    }
    __syncthreads();
    if (tid < 128) part[(size_t)blockIdx.x * Dd + tid] = bins[tid];
}

// ---------- fallback partial V sums ----------
__global__ __launch_bounds__(256) void vpart_kernel(const float* __restrict__ V,
                                                    float* __restrict__ part) {
    int blk = blockIdx.x, bh = blk >> 3, ch = blk & 7;
    int tid = threadIdx.x, d4 = tid & 31, rg = tid >> 5;
    const fvec4* p = (const fvec4*)(V + ((size_t)bh * Ss + ch * 256) * Dd) + d4;
    fvec4 s = {0.f, 0.f, 0.f, 0.f};
    for (int rr = 0; rr < 32; ++rr) s += p[(size_t)(rg * 32 + rr) * 32];
    __shared__ fvec4 red[256];
    red[tid] = s;
    __syncthreads();
    for (int off = 128; off >= 32; off >>= 1) {
        if (tid < off) red[tid] += red[tid + off];
        __syncthreads();
    }
    if (tid < 32) ((fvec4*)(part + (size_t)blk * Dd))[tid] = red[tid];
}

// ---------- combine partials -> vmean ----------
__global__ __launch_bounds__(128) void vcomb_kernel(const float* __restrict__ part,
                                                    float* __restrict__ vm, int nch) {
    int bh = blockIdx.x, d = threadIdx.x;
    float s = 0.f;
    for (int c = 0; c < nch; ++c) s += part[(size_t)(bh * nch + c) * Dd + d];
    vm[bh * Dd + d] = s * (1.0f / 2048.0f);
}

// ====== flash attention: KVB=32, fragment-ordered DMA dbuf, 40KB LDS ======
// NOTE: no min-waves launch_bounds arg — R3/R7/R9 all spilled from VGPR clamping.
__global__ __launch_bounds__(256) void attn4_kernel(
    const float* __restrict__ Qg, const short* __restrict__ Kf,
    const short* __restrict__ Vf, const int* __restrict__ slen,
    const float* __restrict__ vmean, float* __restrict__ Og)
{
    __shared__ __align__(16) short Ks[2][2048];        // 4KB per buf (first half of K tile)
    __shared__ __align__(16) short Ks2[2][2048];       // 4KB per buf (second half)
    __shared__ __align__(16) short Vs[2][2048];
    __shared__ __align__(16) short Vs2[2][2048];
    __shared__ __align__(16) short Ps[4096];           // 4 waves x 2KB

    const int bid = blockIdx.x;
    const int qslot = bid >> 6, r = bid & 63;
    const int qt = 15 - qslot;                         // deepest q-tiles first
    const int b  = (r >> 3) & 3;                       // every batch on every XCD
    const int h  = (r & 7) | ((r >> 5) << 3);
    const int bh = b * 16 + h;                         // (b,h)'s q-tiles share XCD
    const int len = slen[b];
    const int q0 = qt * QBLK;
    const int tid = threadIdx.x;

    if (q0 >= len) {                                   // fully-invalid: rows = mean(V)
        const fvec4* vm4 = (const fvec4*)(vmean + bh * Dd);
        fvec4 val = vm4[tid & 31];
        float* ob = Og + ((size_t)bh * Ss + q0) * Dd;
        int r0 = tid >> 5;
        #pragma unroll
        for (int i = 0; i < 16; ++i)
            ((fvec4*)(ob + (size_t)(r0 + 8 * i) * Dd))[tid & 31] = val;
        return;
    }

    const int w = tid >> 6, lane = tid & 63;
    const int g = lane >> 4, qc = lane & 15;
    const int qw0 = q0 + w * 32;
    const bool wave_active = (qw0 < len);
    const int lo16 = lane * 16;

    const int kv_end   = min(q0 + QBLK, len);
    const int kv_end_w = min(qw0 + 32, kv_end);
    const int nt = (kv_end + KVB - 1) >> 5;

    const char* KbhB = (const char*)Kf + (size_t)bh * 524288;
    const char* VbhB = (const char*)Vf + (size_t)bh * 524288;

    // each tile = 8KB K frag + 8KB V frag, linear; wave w copies its 2KB quarter
    #define GISSUE(tile_, buf_) do {                                                   \
        const char* kb_ = KbhB + (size_t)(tile_) * 8192 + w * 2048;                    \
        const char* vb_ = VbhB + (size_t)(tile_) * 8192 + w * 2048;                    \
        char* kd_ = (w < 2) ? (char*)Ks[buf_] : (char*)Ks2[buf_];                      \
        char* vd_ = (w < 2) ? (char*)Vs[buf_] : (char*)Vs2[buf_];                      \
        kd_ += (w & 1) * 2048;                                                         \
        vd_ += (w & 1) * 2048;                                                         \
        gld16(kb_ + lo16, kd_);                                                        \
        gld16(kb_ + 1024 + lo16, kd_ + 1024);                                          \
        gld16(vb_ + lo16, vd_);                                                        \
        gld16(vb_ + 1024 + lo16, vd_ + 1024);                                          \
    } while (0)

    GISSUE(0, 0);                                      // tile-0 DMA under Q load

    const float SC = 0.12752870368768582f;             // log2(e)/sqrt(128)
    bf16x8 qf[2][4];
    #pragma unroll
    for (int t2 = 0; t2 < 2; ++t2) {
        const float* qrow = Qg + ((size_t)bh * Ss + (qw0 + 16 * t2 + qc)) * Dd;
        #pragma unroll
        for (int kc = 0; kc < 4; ++kc) {
            const fvec4* p = (const fvec4*)(qrow + kc * 32 + g * 8);
            fvec4 a = p[0], bv = p[1];
            unsigned* fu = (unsigned*)&qf[t2][kc];
            fu[0] = pk2(a[0] * SC, a[1] * SC);
            fu[1] = pk2(a[2] * SC, a[3] * SC);
            fu[2] = pk2(bv[0] * SC, bv[1] * SC);
            fu[3] = pk2(bv[2] * SC, bv[3] * SC);
        }
    }

    asm volatile("s_waitcnt vmcnt(0)" ::: "memory");
    __syncthreads();

    f32x4 o[2][8];
    #pragma unroll
    for (int t2 = 0; t2 < 2; ++t2)
        #pragma unroll
        for (int dt = 0; dt < 8; ++dt) o[t2][dt] = (f32x4){0.f, 0.f, 0.f, 0.f};
    float m_[2]   = {-3e38f, -3e38f};
    float lsum[2] = {0.f, 0.f};

    char* PsB = (char*)Ps + w * 2048;                  // 2KB per wave
    const int sw0 = (qc ^ (qc >> 2)) & 3;              // Ps granule swizzle

    for (int t = 0; t < nt; ++t) {
        const int kv0 = t * KVB;
        const int cur = t & 1;
        const bool pre = (t + 1 < nt);
        const bool active = wave_active && (kv0 < kv_end_w);

        if (pre) GISSUE(t + 1, cur ^ 1);               // next-tile DMA under compute

        if (active) {
            const char* KsA = (const char*)Ks[cur];
            const char* KsB2 = (const char*)Ks2[cur];
            const char* VsA = (const char*)Vs[cur];
            const char* VsB2 = (const char*)Vs2[cur];

            // ---- QK^T: A-frags linear from LDS ----
            f32x4 sa[2][2];
            #pragma unroll
            for (int t2 = 0; t2 < 2; ++t2)
                #pragma unroll
                for (int mt = 0; mt < 2; ++mt) sa[t2][mt] = (f32x4){0.f, 0.f, 0.f, 0.f};
            __builtin_amdgcn_s_setprio(1);
            #pragma unroll
            for (int mt = 0; mt < 2; ++mt) {
                bf16x8 kf[4];
                #pragma unroll
                for (int kc = 0; kc < 4; ++kc) {
                    int chunk = mt * 4 + kc;           // [0,8) -> 8KB across Ks/Ks2
                    const char* base = (chunk < 4) ? KsA : KsB2;
                    kf[kc] = *(const bf16x8*)(base + (chunk & 3) * 1024 + lo16);
                }
                #pragma unroll
                for (int t2 = 0; t2 < 2; ++t2)
                    #pragma unroll
                    for (int kc = 0; kc < 4; ++kc)
                        sa[t2][mt] = __builtin_amdgcn_mfma_f32_16x16x32_bf16(
                            kf[kc], qf[t2][kc], sa[t2][mt], 0, 0, 0);
            }
            __builtin_amdgcn_s_setprio(0);

            // ---- mask + online softmax (defer-max) ----
            #pragma unroll
            for (int t2 = 0; t2 < 2; ++t2) {
                const int qrow = qw0 + 16 * t2 + qc;
                const bool full = (kv0 + KVB - 1) <= (qw0 + 16 * t2);
                if (!full) {
                    #pragma unroll
                    for (int mt = 0; mt < 2; ++mt)
                        #pragma unroll
                        for (int rr = 0; rr < 4; ++rr) {
                            int kk = kv0 + mt * 16 + g * 4 + rr;
                            if (kk > qrow) sa[t2][mt][rr] = -3e38f;
                        }
                }
                float tm = fmaxf(
                    fmaxf(fmaxf(sa[t2][0][0], sa[t2][0][1]), fmaxf(sa[t2][0][2], sa[t2][0][3])),
                    fmaxf(fmaxf(sa[t2][1][0], sa[t2][1][1]), fmaxf(sa[t2][1][2], sa[t2][1][3])));
                tm = fmaxf(tm, __shfl_xor(tm, 16));
                tm = fmaxf(tm, __shfl_xor(tm, 32));
                if (__any(tm > m_[t2] + 8.0f)) {
                    float mnew = fmaxf(m_[t2], tm);
                    float al = exp2f(m_[t2] - mnew);
                    m_[t2] = mnew;
                    lsum[t2] *= al;
                    #pragma unroll
                    for (int rr = 0; rr < 4; ++rr) {
                        float alr = __shfl(al, g * 4 + rr);
                        #pragma unroll
                        for (int dt = 0; dt < 8; ++dt) o[t2][dt][rr] *= alr;
                    }
                }
                float mref = m_[t2];
                float ls = 0.f;
                int prow = t2 * 16 + qc;
                #pragma unroll
                for (int mt = 0; mt < 2; ++mt) {
                    f32x4 p;
                    #pragma unroll
                    for (int rr = 0; rr < 4; ++rr)
                        p[rr] = exp2f(sa[t2][mt][rr] - mref);
                    ls += (p[0] + p[1]) + (p[2] + p[3]);
                    u32x2 pw;
                    pw[0] = pk2(p[0], p[1]);
                    pw[1] = pk2(p[2], p[3]);
                    int bo = prow * 64 + (((mt * 2 + (g >> 1)) ^ sw0) * 16) + (g & 1) * 8;
                    *(u32x2*)(PsB + bo) = pw;
                }
                lsum[t2] += ls;
            }

            // ---- PV: P-frag from Ps, B-frags linear from LDS ----
            bf16x8 ap[2];
            #pragma unroll
            for (int t2 = 0; t2 < 2; ++t2) {
                int prow = t2 * 16 + qc;
                ap[t2] = *(const bf16x8*)(PsB + prow * 64 + ((g ^ sw0) * 16));
            }
            __builtin_amdgcn_s_setprio(1);
            #pragma unroll
            for (int dt = 0; dt < 8; ++dt) {
                const char* base = (dt < 4) ? VsA : VsB2;
                bf16x8 bfv = *(const bf16x8*)(base + (dt & 3) * 1024 + lo16);
                #pragma unroll
                for (int t2 = 0; t2 < 2; ++t2)
                    o[t2][dt] = __builtin_amdgcn_mfma_f32_16x16x32_bf16(
                        ap[t2], bfv, o[t2][dt], 0, 0, 0);
            }
            __builtin_amdgcn_s_setprio(0);
        }

        asm volatile("s_waitcnt vmcnt(0)" ::: "memory");
        __syncthreads();
    }
    #undef GISSUE

    // ---- epilogue ----
    float inv_[2][4];
    #pragma unroll
    for (int t2 = 0; t2 < 2; ++t2) {
        float L = lsum[t2];
        L += __shfl_xor(L, 16);
        L += __shfl_xor(L, 32);
        #pragma unroll
        for (int rr = 0; rr < 4; ++rr) {
            float Lr = __shfl(L, g * 4 + rr);
            inv_[t2][rr] = 1.0f / Lr;
        }
    }
    bool needvm = (qw0 + 32 > len);
    float vmv[8];
    #pragma unroll
    for (int dt = 0; dt < 8; ++dt)
        vmv[dt] = needvm ? vmean[bh * Dd + dt * 16 + qc] : 0.f;
    #pragma unroll
    for (int t2 = 0; t2 < 2; ++t2)
        #pragma unroll
        for (int rr = 0; rr < 4; ++rr) {
            int rowg = qw0 + t2 * 16 + g * 4 + rr;
            float* orow = Og + ((size_t)bh * Ss + rowg) * Dd + qc;
            #pragma unroll
            for (int dt = 0; dt < 8; ++dt) {
                float val = o[t2][dt][rr] * inv_[t2][rr];
                if (rowg >= len) val = vmv[dt];
                orow[dt * 16] = val;
            }
        }
}

// ================= fallback (ws too small): 4-wave in-kernel cvt (R4-proven) ======
__global__ __launch_bounds__(256, 2) void attn_fb_kernel(
    const float* __restrict__ Qg, const float* __restrict__ Kg,
    const float* __restrict__ Vg, const int* __restrict__ slen,
    const float* __restrict__ vmean, float* __restrict__ Og)
{
    __shared__ __align__(16) short Ks[64 * Dd];
    __shared__ __align__(16) short Vt[Dd * 64];
    __shared__ __align__(16) short Ps[4 * 32 * 64];

    const int bid = blockIdx.x;
    const int qslot = bid >> 6, r = bid & 63;
    const int qt = 15 - qslot;
    const int b  = (r >> 3) & 3;
    const int h  = (r & 7) | ((r >> 5) << 3);
    const int bh = b * 16 + h;
    const int len = slen[b];
    const int q0 = qt * QBLK;
    const int tid = threadIdx.x;

    if (q0 >= len) {
        const fvec4* vm4 = (const fvec4*)(vmean + bh * Dd);
        fvec4 val = vm4[tid & 31];
        float* ob = Og + ((size_t)bh * Ss + q0) * Dd;
        int r0 = tid >> 5;
        #pragma unroll
        for (int i = 0; i < 16; ++i)
            ((fvec4*)(ob + (size_t)(r0 + 8 * i) * Dd))[tid & 31] = val;
        return;
    }

    const int w = tid >> 6, lane = tid & 63;
    const int g = lane >> 4, qc = lane & 15;
    const int qw0 = q0 + w * 32;
    const bool wave_active = (qw0 < len);

    const int kv_end   = min(q0 + QBLK, len);
    const int kv_end_w = min(qw0 + 32, kv_end);
    const int nt = (kv_end + 63) >> 6;

    const float SC = 0.12752870368768582f;
    bf16x8 qf[2][4];
    #pragma unroll
    for (int t2 = 0; t2 < 2; ++t2) {
        const float* qrow = Qg + ((size_t)bh * Ss + (qw0 + 16 * t2 + qc)) * Dd;
        #pragma unroll
        for (int kc = 0; kc < 4; ++kc) {
            const fvec4* p = (const fvec4*)(qrow + kc * 32 + g * 8);
            fvec4 a = p[0], bv = p[1];
            unsigned* fu = (unsigned*)&qf[t2][kc];
            fu[0] = pk2(a[0] * SC, a[1] * SC);
            fu[1] = pk2(a[2] * SC, a[3] * SC);
            fu[2] = pk2(bv[0] * SC, bv[1] * SC);
            fu[3] = pk2(bv[2] * SC, bv[3] * SC);
        }
    }

    f32x4 o[2][8];
    #pragma unroll
    for (int t2 = 0; t2 < 2; ++t2)
        #pragma unroll
        for (int dt = 0; dt < 8; ++dt) o[t2][dt] = (f32x4){0.f, 0.f, 0.f, 0.f};
    float m_[2]   = {-3e38f, -3e38f};
    float lsum[2] = {0.f, 0.f};
    char* PsB = (char*)Ps + w * 4096;

    for (int t = 0; t < nt; ++t) {
        const int kv0 = t * 64;
        const bool active = wave_active && (kv0 < kv_end_w);
        __syncthreads();
        {
            const fvec4* sk = (const fvec4*)(Kg + ((size_t)bh * Ss + kv0) * Dd);
            #pragma unroll
            for (int i = 0; i < 8; ++i) {
                int f = tid + 256 * i;
                int kr = f >> 5, d4 = f & 31;
                fvec4 v = sk[(size_t)kr * 32 + d4];
                u32x2 pr; pr[0] = pk2(v[0], v[1]); pr[1] = pk2(v[2], v[3]);
                int j = d4 >> 1;
                int js = (j & 8) | ((j & 7) ^ (kr & 7));
                *(u32x2*)((char*)Ks + kr * 256 + js * 16 + (d4 & 1) * 8) = pr;
            }
            const float* sv = Vg + ((size_t)bh * Ss + kv0) * Dd;
            #pragma unroll
            for (int i = 0; i < 2; ++i) {
                int idx = tid + 256 * i;
                int dt4 = idx & 31, kt4 = idx >> 5;
                fvec4 vv[4];
                #pragma unroll
                for (int jj = 0; jj < 4; ++jj)
                    vv[jj] = ((const fvec4*)(sv + (size_t)(kt4 * 4 + jj) * Dd))[dt4];
                #pragma unroll
                for (int jj = 0; jj < 4; ++jj) {
                    int d = dt4 * 4 + jj;
                    u32x2 pr;
                    pr[0] = pk2(vv[0][jj], vv[1][jj]);
                    pr[1] = pk2(vv[2][jj], vv[3][jj]);
                    int bo = d * 128 + ((kt4 >> 1) ^ (d & 7)) * 16 + (kt4 & 1) * 8;
                    *(u32x2*)((char*)Vt + bo) = pr;
                }
            }
        }
        __syncthreads();

        if (active) {
            f32x4 sa[2][4];
            #pragma unroll
            for (int t2 = 0; t2 < 2; ++t2)
                #pragma unroll
                for (int mt = 0; mt < 4; ++mt) sa[t2][mt] = (f32x4){0.f, 0.f, 0.f, 0.f};
            #pragma unroll
            for (int mt = 0; mt < 4; ++mt) {
                int row = mt * 16 + qc;
                bf16x8 kf[4];
                #pragma unroll
                for (int kc = 0; kc < 4; ++kc) {
                    int jb = kc * 4 + g;
                    int js = (jb & 8) | ((jb & 7) ^ (row & 7));
                    kf[kc] = *(const bf16x8*)((const char*)Ks + row * 256 + js * 16);
                }
                #pragma unroll
                for (int t2 = 0; t2 < 2; ++t2)
                    #pragma unroll
                    for (int kc = 0; kc < 4; ++kc)
                        sa[t2][mt] = __builtin_amdgcn_mfma_f32_16x16x32_bf16(
                            kf[kc], qf[t2][kc], sa[t2][mt], 0, 0, 0);
            }
            #pragma unroll
            for (int t2 = 0; t2 < 2; ++t2) {
                const int qrow = qw0 + 16 * t2 + qc;
                const bool full = (kv0 + 63) <= (qw0 + 16 * t2);
                if (!full) {
                    #pragma unroll
                    for (int mt = 0; mt < 4; ++mt)
                        #pragma unroll
                        for (int rr = 0; rr < 4; ++rr) {
                            int kk = kv0 + mt * 16 + g * 4 + rr;
                            if (kk > qrow) sa[t2][mt][rr] = -3e38f;
                        }
                }
                float tm = sa[t2][0][0];
                #pragma unroll
                for (int mt = 0; mt < 4; ++mt)
                    #pragma unroll
                    for (int rr = 0; rr < 4; ++rr) tm = fmaxf(tm, sa[t2][mt][rr]);
                tm = fmaxf(tm, __shfl_xor(tm, 16));
                tm = fmaxf(tm, __shfl_xor(tm, 32));
                if (__any(tm > m_[t2] + 8.0f)) {
                    float mnew = fmaxf(m_[t2], tm);
                    float al = exp2f(m_[t2] - mnew);
                    m_[t2] = mnew;
                    lsum[t2] *= al;
                    #pragma unroll
                    for (int rr = 0; rr < 4; ++rr) {
                        float alr = __shfl(al, g * 4 + rr);
                        #pragma unroll
                        for (int dt = 0; dt < 8; ++dt) o[t2][dt][rr] *= alr;
                    }
                }
                float mref = m_[t2];
                float ls = 0.f;
                int prow = t2 * 16 + qc;
                int pswz = (prow & 7) << 4;
                #pragma unroll
                for (int mt = 0; mt < 4; ++mt) {
                    f32x4 p;
                    #pragma unroll
                    for (int rr = 0; rr < 4; ++rr)
                        p[rr] = exp2f(sa[t2][mt][rr] - mref);
                    ls += (p[0] + p[1]) + (p[2] + p[3]);
                    u32x2 pw;
                    pw[0] = pk2(p[0], p[1]);
                    pw[1] = pk2(p[2], p[3]);
                    *(u32x2*)(PsB + ((prow * 128 + mt * 32 + g * 8) ^ pswz)) = pw;
                }
                lsum[t2] += ls;
            }
            bf16x8 ap[2][2];
            #pragma unroll
            for (int t2 = 0; t2 < 2; ++t2) {
                int prow = t2 * 16 + qc;
                int pswz = (prow & 7) << 4;
                #pragma unroll
                for (int c = 0; c < 2; ++c)
                    ap[t2][c] = *(const bf16x8*)(PsB + ((prow * 128 + c * 64 + g * 16) ^ pswz));
            }
            #pragma unroll
            for (int dt = 0; dt < 8; ++dt) {
                int d = dt * 16 + qc;
                #pragma unroll
                for (int c = 0; c < 2; ++c) {
                    int js = (c * 4 + g) ^ (d & 7);
                    bf16x8 bfv = *(const bf16x8*)((const char*)Vt + d * 128 + js * 16);
                    #pragma unroll
                    for (int t2 = 0; t2 < 2; ++t2)
                        o[t2][dt] = __builtin_amdgcn_mfma_f32_16x16x32_bf16(
                            ap[t2][c], bfv, o[t2][dt], 0, 0, 0);
                }
            }
        }
    }

    float inv_[2][4];
    #pragma unroll
    for (int t2 = 0; t2 < 2; ++t2) {
        float L = lsum[t2];
        L += __shfl_xor(L, 16);
        L += __shfl_xor(L, 32);
        #pragma unroll
        for (int rr = 0; rr < 4; ++rr) {
            float Lr = __shfl(L, g * 4 + rr);
            inv_[t2][rr] = 1.0f / Lr;
        }
    }
    bool needvm = (qw0 + 32 > len);
    float vmv[8];
    #pragma unroll
    for (int dt = 0; dt < 8; ++dt)
        vmv[dt] = needvm ? vmean[bh * Dd + dt * 16 + qc] : 0.f;
    #pragma unroll
    for (int t2 = 0; t2 < 2; ++t2)
        #pragma unroll
        for (int rr = 0; rr < 4; ++rr) {
            int rowg = qw0 + t2 * 16 + g * 4 + rr;
            float* orow = Og + ((size_t)bh * Ss + rowg) * Dd + qc;
            #pragma unroll
            for (int dt = 0; dt < 8; ++dt) {
                float val = o[t2][dt][rr] * inv_[t2][rr];
                if (rowg >= len) val = vmv[dt];
                orow[dt * 16] = val;
            }
        }
}

extern "C" void kernel_launch(void* const* d_in, const int* in_sizes, int n_in,
                              void* d_out, int out_size, void* d_ws, size_t ws_size,
                              hipStream_t stream) {
    const float* q  = (const float*)d_in[0];
    const float* k  = (const float*)d_in[1];
    const float* v  = (const float*)d_in[2];
    const int*   sl = (const int*)d_in[3];
    float* out = (float*)d_out;

    const size_t nElem = (size_t)Bb * Hh * Ss * Dd;            // 16,777,216
    const size_t need0 = nElem * 2 * 2 + 2048 * Dd * 4 + 64 * Dd * 4;

    if (ws_size >= need0) {
        short* Kf   = (short*)d_ws;
        short* Vf   = Kf + nElem;
        float* part = (float*)(Vf + nElem);
        float* vm   = part + 2048 * Dd;
        cvtkf_kernel<<<dim3(2048), dim3(256), 0, stream>>>(k, Kf);
        cvtvf_kernel<<<dim3(2048), dim3(256), 0, stream>>>(v, Vf, part);
        vcomb_kernel<<<dim3(Bb * Hh), dim3(128), 0, stream>>>(part, vm, 32);
        attn4_kernel<<<dim3(1024), dim3(256), 0, stream>>>(q, Kf, Vf, sl, vm, out);
    } else {
        float* part = (float*)d_ws;
        float* vm   = part + 512 * Dd;
        vpart_kernel<<<dim3(512), dim3(256), 0, stream>>>(v, part);
        vcomb_kernel<<<dim3(Bb * Hh), dim3(128), 0, stream>>>(part, vm, 8);
        attn_fb_kernel<<<dim3(1024), dim3(256), 0, stream>>>(q, k, v, sl, vm, out);
    }
}